// Round 18
// baseline (123.760 us; speedup 1.0000x reference)
//
#include <hip/hip_runtime.h>
#include <math.h>
#include <stdint.h>

#define N_NODES 50000
#define N_EDGES 800000
#define NT_TYPES 2
#define ET_TYPES 2
#define NB_SCAN ((N_NODES + 255) / 256)   // 196
#define M_COLS 320                         // 64 q + 2et*128 interleaved (katt,vmsg)
#define M_PER_T (64 * M_COLS)              // 20480 elems per type
#define PROJ_GRID ((N_NODES + 63) / 64)    // 782 proj blocks per type
#define EDGE_GRID ((N_EDGES + 255) / 256)  // 3125
#define AGG_GRID ((N_NODES + 15) / 16)     // per type
#define MAXDEG 64                          // deg ~ Poisson(16): P(>64) ~ 1e-18
#define LOG2E 1.44269504088896f
#define HSTRIDE 36                         // LDS dwords per h row (144B, 16B-aligned)

typedef __attribute__((ext_vector_type(8))) short short8v;   // 8 bf16 (4 VGPR)
typedef __attribute__((ext_vector_type(4))) float float4v;   // MFMA C/D

__device__ __forceinline__ unsigned int f32_to_bf16(float f) {
  unsigned int u = __float_as_uint(f);
  return (u + 0x7FFFu + ((u >> 16) & 1u)) >> 16;   // RNE
}

// Sum over each 16-lane head group via DPP row rotations (ror 8/4/2/1).
__device__ __forceinline__ float row16_sum(float p) {
  int r;
  r = __builtin_amdgcn_update_dpp(0, __float_as_int(p), 0x128, 0xf, 0xf, false);
  p += __int_as_float(r);   // ror:8
  r = __builtin_amdgcn_update_dpp(0, __float_as_int(p), 0x124, 0xf, 0xf, false);
  p += __int_as_float(r);   // ror:4
  r = __builtin_amdgcn_update_dpp(0, __float_as_int(p), 0x122, 0xf, 0xf, false);
  p += __int_as_float(r);   // ror:2
  r = __builtin_amdgcn_update_dpp(0, __float_as_int(p), 0x121, 0xf, 0xf, false);
  p += __int_as_float(r);   // ror:1
  return p;
}

// ---------------------------------------------------------------------------
// Zero kernel (R16: runtime fill kernel is slow; one int per thread).
// ---------------------------------------------------------------------------
__global__ void zero_kernel(int* __restrict__ deg) {
  const int i = blockIdx.x * 256 + threadIdx.x;
  if (i < N_NODES + 2) deg[i] = 0;   // covers deg[N] + tcnt[2] (contiguous)
}

// ---------------------------------------------------------------------------
// Prep+build: fold weights (col-major bf16 M2b/Wa2b; pri*0.25*log2e folded
// into katt columns), cast x to bf16, per-type node lists, and (R17) the CSR
// fill fused with the degree count: the count atomic's return IS the rank,
// so scatter csr[dst*64+rank] = (et*N+src)<<6 immediately -- no rank array,
// no second edge pass.
// ---------------------------------------------------------------------------
__global__ void prep_build_kernel(
    const float* __restrict__ Wk, const float* __restrict__ Wq,
    const float* __restrict__ Wv, const float* __restrict__ Wa,
    const float* __restrict__ Ratt, const float* __restrict__ Rmsg,
    const float* __restrict__ pri,
    const int* __restrict__ dst, const int* __restrict__ src,
    const int* __restrict__ etype, const int* __restrict__ ntype,
    const float* __restrict__ x,
    unsigned short* __restrict__ M2b, unsigned short* __restrict__ Wa2b,
    int* __restrict__ deg, int* __restrict__ tcnt,
    int* __restrict__ tlist, unsigned int* __restrict__ xb,
    int* __restrict__ csr) {
  const int e = blockIdx.x * 256 + threadIdx.x;
  if (e < N_EDGES) {
    int d = dst[e];
    int r = atomicAdd(&deg[d], 1);
    __builtin_nontemporal_store((etype[e] * N_NODES + src[e]) << 6,
                                &csr[(d << 6) + r]);
  }
  if (e < N_NODES * 16) {                   // x -> bf16 (one float4 per thread)
    float4 xa = reinterpret_cast<const float4*>(x)[e];
    xb[2 * e]     = f32_to_bf16(xa.x) | (f32_to_bf16(xa.y) << 16);
    xb[2 * e + 1] = f32_to_bf16(xa.z) | (f32_to_bf16(xa.w) << 16);
  }
  if (e < NT_TYPES * 4096) {                // Wa -> bf16 column-major
    int t = e >> 12;
    int rem = e & 4095;
    int col = rem >> 6, k = rem & 63;
    Wa2b[e] = (unsigned short)f32_to_bf16(Wa[(size_t)t * 4096 + k * 64 + col]);
  }
  if (e < NT_TYPES * M_PER_T) {             // folded proj weights, col-major
    int t = e / M_PER_T;
    int rem = e % M_PER_T;
    int col = rem / 64;
    int k = rem % 64;
    float val;
    if (col < 64) {
      val = Wq[(size_t)t * 4096 + k * 64 + col];
    } else {
      int cc = col - 64;
      int et = cc >> 7;
      int r = cc & 127;
      int c = r >> 1;
      int half = r & 1;
      int h = c >> 4, f = c & 15;
      const float* W = half ? Wv : Wk;
      const float* R = half ? Rmsg : Ratt;
      float s = 0.f;
#pragma unroll
      for (int d = 0; d < 16; ++d)
        s = fmaf(W[(size_t)t * 4096 + k * 64 + h * 16 + d],
                 R[(((size_t)h * ET_TYPES + et) * 16 + d) * 16 + f], s);
      if (half == 0) s *= pri[h * ET_TYPES + et] * 0.25f * LOG2E;  // fold pri
      val = s;
    }
    M2b[e] = (unsigned short)f32_to_bf16(val);
  }
  if (blockIdx.x < NB_SCAN) {               // per-type node lists
    __shared__ int lcnt[NT_TYPES];
    __shared__ int lbase[NT_TYPES];
    if (threadIdx.x < NT_TYPES) lcnt[threadIdx.x] = 0;
    __syncthreads();
    int t = 0, lpos = 0;
    const bool valid = (e < N_NODES);
    if (valid) {
      t = ntype[e];
      lpos = atomicAdd(&lcnt[t], 1);        // LDS atomic
    }
    __syncthreads();
    if (threadIdx.x < NT_TYPES)
      lbase[threadIdx.x] = atomicAdd(&tcnt[threadIdx.x], lcnt[threadIdx.x]);
    __syncthreads();
    if (valid)
      tlist[t * N_NODES + lbase[t] + lpos] = e;
  }
}

// ---------------------------------------------------------------------------
// MFMA projection (proj-only now; fill lives in prep_build): 16 nodes/wave,
// 20 col-tiles x 2 K-steps; C layout per m89. q stored as bf16.
// ---------------------------------------------------------------------------
__global__ __launch_bounds__(256) void proj_kernel(
    const unsigned short* __restrict__ xb,
    const unsigned short* __restrict__ M2b,
    const int* __restrict__ tcnt, const int* __restrict__ tlist,
    unsigned short* __restrict__ qb, unsigned int* __restrict__ kvb) {
  const int ty = blockIdx.x & 1;
  const int pb = blockIdx.x >> 1;
  const int wave = threadIdx.x >> 6;
  const int lane = threadIdx.x & 63;
  const int cnt = __builtin_amdgcn_readfirstlane(tcnt[ty]);
  const int base = (pb * 4 + wave) * 16;
  if (base >= cnt) return;

  const int* lst = tlist + ty * N_NODES;
  const int l15 = lane & 15;
  const int lq = lane >> 4;

  const int nidA = lst[min(base + l15, cnt - 1)];
  const short8v A0 = *reinterpret_cast<const short8v*>(
      xb + (size_t)nidA * 64 + lq * 8);
  const short8v A1 = *reinterpret_cast<const short8v*>(
      xb + (size_t)nidA * 64 + 32 + lq * 8);

  const int n0 = lst[min(base + lq * 4 + 0, cnt - 1)];
  const int n1 = lst[min(base + lq * 4 + 1, cnt - 1)];
  const int n2 = lst[min(base + lq * 4 + 2, cnt - 1)];
  const int n3 = lst[min(base + lq * 4 + 3, cnt - 1)];

  const unsigned short* Bb = M2b + (size_t)ty * M_PER_T;

#pragma unroll
  for (int ct = 0; ct < 20; ++ct) {
    const int colb = ct * 16 + l15;
    const short8v B0 = *reinterpret_cast<const short8v*>(
        Bb + (size_t)colb * 64 + lq * 8);
    const short8v B1 = *reinterpret_cast<const short8v*>(
        Bb + (size_t)colb * 64 + 32 + lq * 8);
    float4v C = {0.f, 0.f, 0.f, 0.f};
    C = __builtin_amdgcn_mfma_f32_16x16x32_bf16(A0, B0, C, 0, 0, 0);
    C = __builtin_amdgcn_mfma_f32_16x16x32_bf16(A1, B1, C, 0, 0, 0);

    if (ct < 4) {                           // q columns: bf16 store
      qb[(size_t)n0 * 64 + colb] = (unsigned short)f32_to_bf16(C[0]);
      qb[(size_t)n1 * 64 + colb] = (unsigned short)f32_to_bf16(C[1]);
      qb[(size_t)n2 * 64 + colb] = (unsigned short)f32_to_bf16(C[2]);
      qb[(size_t)n3 * 64 + colb] = (unsigned short)f32_to_bf16(C[3]);
    } else {                                // kv columns: pack bf16x2 pairs
      const float p0 = __shfl_xor(C[0], 1, 64);
      const float p1 = __shfl_xor(C[1], 1, 64);
      const float p2 = __shfl_xor(C[2], 1, 64);
      const float p3 = __shfl_xor(C[3], 1, 64);
      if ((lane & 1) == 0) {                // even lane = katt, partner = vmsg
        const int cc = colb - 64;
        const int et = cc >> 7;
        const int c = (cc & 127) >> 1;
        const size_t b0 = ((size_t)et * N_NODES) * 64 + c;
        kvb[b0 + (size_t)n0 * 64] = f32_to_bf16(C[0]) | (f32_to_bf16(p0) << 16);
        kvb[b0 + (size_t)n1 * 64] = f32_to_bf16(C[1]) | (f32_to_bf16(p1) << 16);
        kvb[b0 + (size_t)n2 * 64] = f32_to_bf16(C[2]) | (f32_to_bf16(p2) << 16);
        kvb[b0 + (size_t)n3 * 64] = f32_to_bf16(C[3]) | (f32_to_bf16(p3) << 16);
      }
    }
  }
}

// ---------------------------------------------------------------------------
// Fused aggregate + output. Phase 1 (R17): waves process their 4 nodes as
// TWO interleaved pairs -- independent (srun,acc) chains give 8 gathers in
// flight (agg was half-latency-bound at 53% occupancy). Phase 2: wave w
// computes out col-tile w via 2 MFMAs + sigmoid-skip blend.
// ---------------------------------------------------------------------------
__device__ __forceinline__ void edge_update(unsigned int wrd, float qd,
                                            float& srun, float& acc) {
  float kw = __uint_as_float(wrd << 16);            // low bf16 = katt (scaled)
  float mv = __uint_as_float(wrd & 0xFFFF0000u);    // high bf16 = vmsg
  float w = __builtin_amdgcn_exp2f(row16_sum(kw * qd));
  srun += w;
  acc = fmaf(mv, w, acc);
}

__global__ __launch_bounds__(256) void agg_out_kernel(
    const unsigned short* __restrict__ qb, const unsigned int* __restrict__ kvb,
    const int* __restrict__ deg, const int* __restrict__ csr,
    const unsigned short* __restrict__ Wa2b, const float* __restrict__ x,
    const float* __restrict__ skip, const int* __restrict__ tcnt,
    const int* __restrict__ tlist, float* __restrict__ out) {
  __shared__ unsigned int hlds[16 * HSTRIDE];
  const int wave = threadIdx.x >> 6;
  const int lane = threadIdx.x & 63;
  const int ty = blockIdx.y;
  const int cnt = __builtin_amdgcn_readfirstlane(tcnt[ty]);
  const int base = blockIdx.x * 16;
  if (base >= cnt) return;
  const int* lst = tlist + ty * N_NODES;

  // ---- phase 1: two interleaved node-pairs per wave ----
  for (int half = 0; half < 2; ++half) {
    const int lrowA = wave * 4 + half * 2;
    int nA = __builtin_amdgcn_readfirstlane(lst[min(base + lrowA, cnt - 1)]);
    int nB = __builtin_amdgcn_readfirstlane(lst[min(base + lrowA + 1, cnt - 1)]);
    const float qdA = __uint_as_float((unsigned int)qb[(size_t)nA * 64 + lane] << 16);
    const float qdB = __uint_as_float((unsigned int)qb[(size_t)nB * 64 + lane] << 16);
    const int eA = __builtin_amdgcn_readfirstlane(deg[nA]);
    const int eB = __builtin_amdgcn_readfirstlane(deg[nB]);
    const int* cA = csr + (nA << 6);
    const int* cB = csr + (nB << 6);

    float sA = 0.f, aA = 0.f, sB = 0.f, aB = 0.f;
    const int m = min(eA, eB);
    int j = 0;
    for (; j + 4 <= m; j += 4) {            // joint: 8 gathers in flight
      int pA0 = __builtin_amdgcn_readfirstlane(cA[j + 0]);
      int pA1 = __builtin_amdgcn_readfirstlane(cA[j + 1]);
      int pA2 = __builtin_amdgcn_readfirstlane(cA[j + 2]);
      int pA3 = __builtin_amdgcn_readfirstlane(cA[j + 3]);
      int pB0 = __builtin_amdgcn_readfirstlane(cB[j + 0]);
      int pB1 = __builtin_amdgcn_readfirstlane(cB[j + 1]);
      int pB2 = __builtin_amdgcn_readfirstlane(cB[j + 2]);
      int pB3 = __builtin_amdgcn_readfirstlane(cB[j + 3]);
      unsigned int wA0 = kvb[(unsigned)pA0 + lane];
      unsigned int wA1 = kvb[(unsigned)pA1 + lane];
      unsigned int wA2 = kvb[(unsigned)pA2 + lane];
      unsigned int wA3 = kvb[(unsigned)pA3 + lane];
      unsigned int wB0 = kvb[(unsigned)pB0 + lane];
      unsigned int wB1 = kvb[(unsigned)pB1 + lane];
      unsigned int wB2 = kvb[(unsigned)pB2 + lane];
      unsigned int wB3 = kvb[(unsigned)pB3 + lane];
      edge_update(wA0, qdA, sA, aA);
      edge_update(wB0, qdB, sB, aB);
      edge_update(wA1, qdA, sA, aA);
      edge_update(wB1, qdB, sB, aB);
      edge_update(wA2, qdA, sA, aA);
      edge_update(wB2, qdB, sB, aB);
      edge_update(wA3, qdA, sA, aA);
      edge_update(wB3, qdB, sB, aB);
    }
    int jA = j;
    for (; jA + 4 <= eA; jA += 4) {
      int p0 = __builtin_amdgcn_readfirstlane(cA[jA + 0]);
      int p1 = __builtin_amdgcn_readfirstlane(cA[jA + 1]);
      int p2 = __builtin_amdgcn_readfirstlane(cA[jA + 2]);
      int p3 = __builtin_amdgcn_readfirstlane(cA[jA + 3]);
      unsigned int w0 = kvb[(unsigned)p0 + lane];
      unsigned int w1 = kvb[(unsigned)p1 + lane];
      unsigned int w2 = kvb[(unsigned)p2 + lane];
      unsigned int w3 = kvb[(unsigned)p3 + lane];
      edge_update(w0, qdA, sA, aA);
      edge_update(w1, qdA, sA, aA);
      edge_update(w2, qdA, sA, aA);
      edge_update(w3, qdA, sA, aA);
    }
    for (; jA < eA; ++jA) {
      int p = __builtin_amdgcn_readfirstlane(cA[jA]);
      edge_update(kvb[(unsigned)p + lane], qdA, sA, aA);
    }
    int jB = j;
    for (; jB + 4 <= eB; jB += 4) {
      int p0 = __builtin_amdgcn_readfirstlane(cB[jB + 0]);
      int p1 = __builtin_amdgcn_readfirstlane(cB[jB + 1]);
      int p2 = __builtin_amdgcn_readfirstlane(cB[jB + 2]);
      int p3 = __builtin_amdgcn_readfirstlane(cB[jB + 3]);
      unsigned int w0 = kvb[(unsigned)p0 + lane];
      unsigned int w1 = kvb[(unsigned)p1 + lane];
      unsigned int w2 = kvb[(unsigned)p2 + lane];
      unsigned int w3 = kvb[(unsigned)p3 + lane];
      edge_update(w0, qdB, sB, aB);
      edge_update(w1, qdB, sB, aB);
      edge_update(w2, qdB, sB, aB);
      edge_update(w3, qdB, sB, aB);
    }
    for (; jB < eB; ++jB) {
      int p = __builtin_amdgcn_readfirstlane(cB[jB]);
      edge_update(kvb[(unsigned)p + lane], qdB, sB, aB);
    }

    float hvA = (sA > 0.f) ? (aA / sA) : 0.f;
    float hvB = (sB > 0.f) ? (aB / sB) : 0.f;
    float prA = __shfl_xor(hvA, 1, 64);
    float prB = __shfl_xor(hvB, 1, 64);
    if ((lane & 1) == 0) {
      hlds[lrowA * HSTRIDE + (lane >> 1)] =
          f32_to_bf16(hvA) | (f32_to_bf16(prA) << 16);
      hlds[(lrowA + 1) * HSTRIDE + (lane >> 1)] =
          f32_to_bf16(hvB) | (f32_to_bf16(prB) << 16);
    }
  }
  __syncthreads();

  // ---- phase 2: out = (h @ Wa[ty]) * alpha + x * (1-alpha) ----
  const int l15 = lane & 15;
  const int lq = lane >> 4;
  const short8v A0 = *reinterpret_cast<const short8v*>(&hlds[l15 * HSTRIDE + lq * 4]);
  const short8v A1 = *reinterpret_cast<const short8v*>(&hlds[l15 * HSTRIDE + 16 + lq * 4]);

  const int n0 = lst[min(base + lq * 4 + 0, cnt - 1)];
  const int n1 = lst[min(base + lq * 4 + 1, cnt - 1)];
  const int n2 = lst[min(base + lq * 4 + 2, cnt - 1)];
  const int n3 = lst[min(base + lq * 4 + 3, cnt - 1)];

  const float alpha = 1.f / (1.f + __expf(-skip[ty]));
  const float beta = 1.f - alpha;
  const unsigned short* Bb = Wa2b + (size_t)ty * 4096;

  const int colb = wave * 16 + l15;         // wave w owns col-tile w
  const short8v B0 = *reinterpret_cast<const short8v*>(
      Bb + (size_t)colb * 64 + lq * 8);
  const short8v B1 = *reinterpret_cast<const short8v*>(
      Bb + (size_t)colb * 64 + 32 + lq * 8);
  float4v C = {0.f, 0.f, 0.f, 0.f};
  C = __builtin_amdgcn_mfma_f32_16x16x32_bf16(A0, B0, C, 0, 0, 0);
  C = __builtin_amdgcn_mfma_f32_16x16x32_bf16(A1, B1, C, 0, 0, 0);

  const size_t o0 = (size_t)n0 * 64 + colb;
  const size_t o1 = (size_t)n1 * 64 + colb;
  const size_t o2 = (size_t)n2 * 64 + colb;
  const size_t o3 = (size_t)n3 * 64 + colb;
  out[o0] = C[0] * alpha + x[o0] * beta;
  out[o1] = C[1] * alpha + x[o1] * beta;
  out[o2] = C[2] * alpha + x[o2] * beta;
  out[o3] = C[3] * alpha + x[o3] * beta;
}

// ---------------------------------------------------------------------------
extern "C" void kernel_launch(void* const* d_in, const int* in_sizes, int n_in,
                              void* d_out, int out_size, void* d_ws, size_t ws_size,
                              hipStream_t stream) {
  const float* x    = (const float*)d_in[0];
  const float* Wk   = (const float*)d_in[1];
  const float* Wq   = (const float*)d_in[2];
  const float* Wv   = (const float*)d_in[3];
  const float* Wa   = (const float*)d_in[4];
  const float* Ratt = (const float*)d_in[5];
  const float* Rmsg = (const float*)d_in[6];
  const float* pri  = (const float*)d_in[7];
  const float* skip = (const float*)d_in[8];
  const int* ntype  = (const int*)d_in[9];
  const int* etype  = (const int*)d_in[10];
  const int* src    = (const int*)d_in[11];
  const int* dst    = (const int*)d_in[12];
  float* out = (float*)d_out;

  // workspace layout
  unsigned short* qb = (unsigned short*)d_ws;           // N*64 bf16
  unsigned int* kvb = (unsigned int*)(qb + (size_t)N_NODES * 64);  // ET*N*64
  unsigned short* xb = (unsigned short*)(kvb + (size_t)ET_TYPES * N_NODES * 64); // N*64 bf16
  int* deg   = (int*)(xb + (size_t)N_NODES * 64);       // N  } zero_kernel
  int* tcnt  = deg + N_NODES;                           // 2  } covers both
  int* tlist = tcnt + 2;                                // 2*N
  int* csr   = tlist + 2 * N_NODES;                     // N*MAXDEG
  unsigned short* M2b = (unsigned short*)
      (((uintptr_t)(csr + (size_t)N_NODES * MAXDEG) + 255) & ~(uintptr_t)255);
  unsigned short* Wa2b = (unsigned short*)
      (((uintptr_t)(M2b + NT_TYPES * M_PER_T) + 255) & ~(uintptr_t)255);

  zero_kernel<<<NB_SCAN, 256, 0, stream>>>(deg);

  prep_build_kernel<<<EDGE_GRID, 256, 0, stream>>>(
      Wk, Wq, Wv, Wa, Ratt, Rmsg, pri, dst, src, etype, ntype, x,
      M2b, Wa2b, deg, tcnt, tlist, (unsigned int*)xb, csr);

  proj_kernel<<<2 * PROJ_GRID, 256, 0, stream>>>(
      xb, M2b, tcnt, tlist, qb, kvb);

  dim3 agrid(AGG_GRID, NT_TYPES);
  agg_out_kernel<<<agrid, 256, 0, stream>>>(
      qb, (const unsigned int*)kvb, deg, csr, Wa2b, x, skip, tcnt, tlist, out);
}

// Round 19
// 115.856 us; speedup vs baseline: 1.0682x; 1.0682x over previous
//
#include <hip/hip_runtime.h>
#include <math.h>
#include <stdint.h>

#define N_NODES 50000
#define N_EDGES 800000
#define NT_TYPES 2
#define ET_TYPES 2
#define NB_SCAN ((N_NODES + 255) / 256)   // 196
#define M_COLS 320                         // 64 q + 2et*128 interleaved (katt,vmsg)
#define M_PER_T (64 * M_COLS)              // 20480 elems per type
#define PROJ_GRID ((N_NODES + 63) / 64)    // 782 proj blocks per type
#define SCAT_GRID ((N_EDGES + 1023) / 1024) // 782 scatter blocks (4 edges/thread)
#define AGG_GRID ((N_NODES + 15) / 16)     // per type
#define MAXDEG 64                          // deg ~ Poisson(16): P(>64) ~ 1e-18
#define LOG2E 1.44269504088896f
#define HSTRIDE 36                         // LDS dwords per h row (144B, 16B-aligned)

typedef __attribute__((ext_vector_type(8))) short short8v;   // 8 bf16 (4 VGPR)
typedef __attribute__((ext_vector_type(4))) float float4v;   // MFMA C/D

__device__ __forceinline__ unsigned int f32_to_bf16(float f) {
  unsigned int u = __float_as_uint(f);
  return (u + 0x7FFFu + ((u >> 16) & 1u)) >> 16;   // RNE
}

// Sum over each 16-lane head group via DPP row rotations (ror 8/4/2/1).
__device__ __forceinline__ float row16_sum(float p) {
  int r;
  r = __builtin_amdgcn_update_dpp(0, __float_as_int(p), 0x128, 0xf, 0xf, false);
  p += __int_as_float(r);   // ror:8
  r = __builtin_amdgcn_update_dpp(0, __float_as_int(p), 0x124, 0xf, 0xf, false);
  p += __int_as_float(r);   // ror:4
  r = __builtin_amdgcn_update_dpp(0, __float_as_int(p), 0x122, 0xf, 0xf, false);
  p += __int_as_float(r);   // ror:2
  r = __builtin_amdgcn_update_dpp(0, __float_as_int(p), 0x121, 0xf, 0xf, false);
  p += __int_as_float(r);   // ror:1
  return p;
}

// ---------------------------------------------------------------------------
// Zero kernel (R16: runtime fill kernel is slow; one int per thread).
// ---------------------------------------------------------------------------
__global__ void zero_kernel(int* __restrict__ deg) {
  const int i = blockIdx.x * 256 + threadIdx.x;
  if (i < N_NODES + 2) deg[i] = 0;   // covers deg[N] + tcnt[2] (contiguous)
}

// ---------------------------------------------------------------------------
// Prep (R18 shrink: fold + tlist only — x-cast deleted, proj converts f32
// in-register; edge scatter moved to the heterogeneous projscatter launch).
// ---------------------------------------------------------------------------
__global__ void prep_kernel(
    const float* __restrict__ Wk, const float* __restrict__ Wq,
    const float* __restrict__ Wv, const float* __restrict__ Wa,
    const float* __restrict__ Ratt, const float* __restrict__ Rmsg,
    const float* __restrict__ pri, const int* __restrict__ ntype,
    unsigned short* __restrict__ M2b, unsigned short* __restrict__ Wa2b,
    int* __restrict__ tcnt, int* __restrict__ tlist) {
  const int idx = blockIdx.x * 256 + threadIdx.x;
  if (idx < NT_TYPES * 4096) {              // Wa -> bf16 column-major
    int t = idx >> 12;
    int rem = idx & 4095;
    int col = rem >> 6, k = rem & 63;
    Wa2b[idx] = (unsigned short)f32_to_bf16(Wa[(size_t)t * 4096 + k * 64 + col]);
  }
  if (idx < NT_TYPES * M_PER_T) {           // folded proj weights, col-major
    int t = idx / M_PER_T;
    int rem = idx % M_PER_T;
    int col = rem / 64;
    int k = rem % 64;
    float val;
    if (col < 64) {
      val = Wq[(size_t)t * 4096 + k * 64 + col];
    } else {
      int cc = col - 64;
      int et = cc >> 7;
      int r = cc & 127;
      int c = r >> 1;
      int half = r & 1;
      int h = c >> 4, f = c & 15;
      const float* W = half ? Wv : Wk;
      const float* R = half ? Rmsg : Ratt;
      float s = 0.f;
#pragma unroll
      for (int d = 0; d < 16; ++d)
        s = fmaf(W[(size_t)t * 4096 + k * 64 + h * 16 + d],
                 R[(((size_t)h * ET_TYPES + et) * 16 + d) * 16 + f], s);
      if (half == 0) s *= pri[h * ET_TYPES + et] * 0.25f * LOG2E;  // fold pri
      val = s;
    }
    M2b[idx] = (unsigned short)f32_to_bf16(val);
  }
  {                                          // per-type node lists
    __shared__ int lcnt[NT_TYPES];
    __shared__ int lbase[NT_TYPES];
    if (threadIdx.x < NT_TYPES) lcnt[threadIdx.x] = 0;
    __syncthreads();
    int t = 0, lpos = 0;
    const bool valid = (idx < N_NODES);
    if (valid) {
      t = ntype[idx];
      lpos = atomicAdd(&lcnt[t], 1);        // LDS atomic
    }
    __syncthreads();
    if (threadIdx.x < NT_TYPES)
      lbase[threadIdx.x] = atomicAdd(&tcnt[threadIdx.x], lcnt[threadIdx.x]);
    __syncthreads();
    if (valid)
      tlist[t * N_NODES + lbase[t] + lpos] = idx;
  }
}

// ---------------------------------------------------------------------------
// Heterogeneous proj + edge-scatter (R18 lesson: scatter is latency-bound at
// VALU 1% while proj is VALU/MFMA-dense — co-schedule them; scatter batched
// 4 edges/thread for MLP: 12 loads -> 4 independent atomics -> 4 stores).
//   blocks [0, 2*PROJ_GRID): MFMA projection, x read as f32 and converted
//     in-register (cast pass deleted). q stored bf16; kv packed bf16x2.
//   blocks [2*PROJ_GRID, +SCAT_GRID): csr[dst*64+rank] = (et*N+src)<<6.
// ---------------------------------------------------------------------------
__global__ __launch_bounds__(256) void projscatter_kernel(
    const float* __restrict__ x,
    const unsigned short* __restrict__ M2b,
    const int* __restrict__ tcnt, const int* __restrict__ tlist,
    unsigned short* __restrict__ qb, unsigned int* __restrict__ kvb,
    const int* __restrict__ src, const int* __restrict__ dst,
    const int* __restrict__ etype, int* __restrict__ deg,
    int* __restrict__ csr) {
  const int bid = blockIdx.x;
  if (bid >= 2 * PROJ_GRID) {               // ---- edge scatter, 4/thread ----
    const int ebase = (bid - 2 * PROJ_GRID) * 1024 + threadIdx.x;
    int dsts[4], recs[4];
#pragma unroll
    for (int k = 0; k < 4; ++k) {
      int e = ebase + k * 256;
      bool v = (e < N_EDGES);
      dsts[k] = v ? dst[e] : -1;
      recs[k] = v ? ((etype[e] * N_NODES + src[e]) << 6) : 0;
    }
#pragma unroll
    for (int k = 0; k < 4; ++k) {
      if (dsts[k] >= 0) {
        int r = atomicAdd(&deg[dsts[k]], 1);
        __builtin_nontemporal_store(recs[k], &csr[(dsts[k] << 6) + r]);
      }
    }
    return;
  }
  // ---- MFMA projection ----
  const int ty = bid & 1;
  const int pb = bid >> 1;
  const int wave = threadIdx.x >> 6;
  const int lane = threadIdx.x & 63;
  const int cnt = __builtin_amdgcn_readfirstlane(tcnt[ty]);
  const int base = (pb * 4 + wave) * 16;
  if (base >= cnt) return;

  const int* lst = tlist + ty * N_NODES;
  const int l15 = lane & 15;
  const int lq = lane >> 4;

  // A fragments: node row read as f32, converted in-register (RNE).
  const int nidA = lst[min(base + l15, cnt - 1)];
  const float4* xr = reinterpret_cast<const float4*>(x + (size_t)nidA * 64);
  const float4 xa0 = xr[lq * 2 + 0];
  const float4 xa1 = xr[lq * 2 + 1];
  const float4 xb0 = xr[8 + lq * 2 + 0];
  const float4 xb1 = xr[8 + lq * 2 + 1];
  union { short8v v; unsigned int u[4]; } A0u, A1u;
  A0u.u[0] = f32_to_bf16(xa0.x) | (f32_to_bf16(xa0.y) << 16);
  A0u.u[1] = f32_to_bf16(xa0.z) | (f32_to_bf16(xa0.w) << 16);
  A0u.u[2] = f32_to_bf16(xa1.x) | (f32_to_bf16(xa1.y) << 16);
  A0u.u[3] = f32_to_bf16(xa1.z) | (f32_to_bf16(xa1.w) << 16);
  A1u.u[0] = f32_to_bf16(xb0.x) | (f32_to_bf16(xb0.y) << 16);
  A1u.u[1] = f32_to_bf16(xb0.z) | (f32_to_bf16(xb0.w) << 16);
  A1u.u[2] = f32_to_bf16(xb1.x) | (f32_to_bf16(xb1.y) << 16);
  A1u.u[3] = f32_to_bf16(xb1.z) | (f32_to_bf16(xb1.w) << 16);
  const short8v A0 = A0u.v;
  const short8v A1 = A1u.v;

  const int n0 = lst[min(base + lq * 4 + 0, cnt - 1)];
  const int n1 = lst[min(base + lq * 4 + 1, cnt - 1)];
  const int n2 = lst[min(base + lq * 4 + 2, cnt - 1)];
  const int n3 = lst[min(base + lq * 4 + 3, cnt - 1)];

  const unsigned short* Bb = M2b + (size_t)ty * M_PER_T;

#pragma unroll
  for (int ct = 0; ct < 20; ++ct) {
    const int colb = ct * 16 + l15;
    const short8v B0 = *reinterpret_cast<const short8v*>(
        Bb + (size_t)colb * 64 + lq * 8);
    const short8v B1 = *reinterpret_cast<const short8v*>(
        Bb + (size_t)colb * 64 + 32 + lq * 8);
    float4v C = {0.f, 0.f, 0.f, 0.f};
    C = __builtin_amdgcn_mfma_f32_16x16x32_bf16(A0, B0, C, 0, 0, 0);
    C = __builtin_amdgcn_mfma_f32_16x16x32_bf16(A1, B1, C, 0, 0, 0);

    if (ct < 4) {                           // q columns: bf16 store
      qb[(size_t)n0 * 64 + colb] = (unsigned short)f32_to_bf16(C[0]);
      qb[(size_t)n1 * 64 + colb] = (unsigned short)f32_to_bf16(C[1]);
      qb[(size_t)n2 * 64 + colb] = (unsigned short)f32_to_bf16(C[2]);
      qb[(size_t)n3 * 64 + colb] = (unsigned short)f32_to_bf16(C[3]);
    } else {                                // kv columns: pack bf16x2 pairs
      const float p0 = __shfl_xor(C[0], 1, 64);
      const float p1 = __shfl_xor(C[1], 1, 64);
      const float p2 = __shfl_xor(C[2], 1, 64);
      const float p3 = __shfl_xor(C[3], 1, 64);
      if ((lane & 1) == 0) {                // even lane = katt, partner = vmsg
        const int cc = colb - 64;
        const int et = cc >> 7;
        const int c = (cc & 127) >> 1;
        const size_t b0 = ((size_t)et * N_NODES) * 64 + c;
        kvb[b0 + (size_t)n0 * 64] = f32_to_bf16(C[0]) | (f32_to_bf16(p0) << 16);
        kvb[b0 + (size_t)n1 * 64] = f32_to_bf16(C[1]) | (f32_to_bf16(p1) << 16);
        kvb[b0 + (size_t)n2 * 64] = f32_to_bf16(C[2]) | (f32_to_bf16(p2) << 16);
        kvb[b0 + (size_t)n3 * 64] = f32_to_bf16(C[3]) | (f32_to_bf16(p3) << 16);
      }
    }
  }
}

// ---------------------------------------------------------------------------
// Fused aggregate + output. Phase 1: waves process their 4 nodes as TWO
// interleaved pairs (independent (srun,acc) chains -> 8 gathers in flight).
// Phase 2: wave w computes out col-tile w via 2 MFMAs + sigmoid-skip blend.
// ---------------------------------------------------------------------------
__device__ __forceinline__ void edge_update(unsigned int wrd, float qd,
                                            float& srun, float& acc) {
  float kw = __uint_as_float(wrd << 16);            // low bf16 = katt (scaled)
  float mv = __uint_as_float(wrd & 0xFFFF0000u);    // high bf16 = vmsg
  float w = __builtin_amdgcn_exp2f(row16_sum(kw * qd));
  srun += w;
  acc = fmaf(mv, w, acc);
}

__global__ __launch_bounds__(256) void agg_out_kernel(
    const unsigned short* __restrict__ qb, const unsigned int* __restrict__ kvb,
    const int* __restrict__ deg, const int* __restrict__ csr,
    const unsigned short* __restrict__ Wa2b, const float* __restrict__ x,
    const float* __restrict__ skip, const int* __restrict__ tcnt,
    const int* __restrict__ tlist, float* __restrict__ out) {
  __shared__ unsigned int hlds[16 * HSTRIDE];
  const int wave = threadIdx.x >> 6;
  const int lane = threadIdx.x & 63;
  const int ty = blockIdx.y;
  const int cnt = __builtin_amdgcn_readfirstlane(tcnt[ty]);
  const int base = blockIdx.x * 16;
  if (base >= cnt) return;
  const int* lst = tlist + ty * N_NODES;

  // ---- phase 1: two interleaved node-pairs per wave ----
  for (int half = 0; half < 2; ++half) {
    const int lrowA = wave * 4 + half * 2;
    int nA = __builtin_amdgcn_readfirstlane(lst[min(base + lrowA, cnt - 1)]);
    int nB = __builtin_amdgcn_readfirstlane(lst[min(base + lrowA + 1, cnt - 1)]);
    const float qdA = __uint_as_float((unsigned int)qb[(size_t)nA * 64 + lane] << 16);
    const float qdB = __uint_as_float((unsigned int)qb[(size_t)nB * 64 + lane] << 16);
    const int eA = __builtin_amdgcn_readfirstlane(deg[nA]);
    const int eB = __builtin_amdgcn_readfirstlane(deg[nB]);
    const int* cA = csr + (nA << 6);
    const int* cB = csr + (nB << 6);

    float sA = 0.f, aA = 0.f, sB = 0.f, aB = 0.f;
    const int m = min(eA, eB);
    int j = 0;
    for (; j + 4 <= m; j += 4) {            // joint: 8 gathers in flight
      int pA0 = __builtin_amdgcn_readfirstlane(cA[j + 0]);
      int pA1 = __builtin_amdgcn_readfirstlane(cA[j + 1]);
      int pA2 = __builtin_amdgcn_readfirstlane(cA[j + 2]);
      int pA3 = __builtin_amdgcn_readfirstlane(cA[j + 3]);
      int pB0 = __builtin_amdgcn_readfirstlane(cB[j + 0]);
      int pB1 = __builtin_amdgcn_readfirstlane(cB[j + 1]);
      int pB2 = __builtin_amdgcn_readfirstlane(cB[j + 2]);
      int pB3 = __builtin_amdgcn_readfirstlane(cB[j + 3]);
      unsigned int wA0 = kvb[(unsigned)pA0 + lane];
      unsigned int wA1 = kvb[(unsigned)pA1 + lane];
      unsigned int wA2 = kvb[(unsigned)pA2 + lane];
      unsigned int wA3 = kvb[(unsigned)pA3 + lane];
      unsigned int wB0 = kvb[(unsigned)pB0 + lane];
      unsigned int wB1 = kvb[(unsigned)pB1 + lane];
      unsigned int wB2 = kvb[(unsigned)pB2 + lane];
      unsigned int wB3 = kvb[(unsigned)pB3 + lane];
      edge_update(wA0, qdA, sA, aA);
      edge_update(wB0, qdB, sB, aB);
      edge_update(wA1, qdA, sA, aA);
      edge_update(wB1, qdB, sB, aB);
      edge_update(wA2, qdA, sA, aA);
      edge_update(wB2, qdB, sB, aB);
      edge_update(wA3, qdA, sA, aA);
      edge_update(wB3, qdB, sB, aB);
    }
    int jA = j;
    for (; jA + 4 <= eA; jA += 4) {
      int p0 = __builtin_amdgcn_readfirstlane(cA[jA + 0]);
      int p1 = __builtin_amdgcn_readfirstlane(cA[jA + 1]);
      int p2 = __builtin_amdgcn_readfirstlane(cA[jA + 2]);
      int p3 = __builtin_amdgcn_readfirstlane(cA[jA + 3]);
      unsigned int w0 = kvb[(unsigned)p0 + lane];
      unsigned int w1 = kvb[(unsigned)p1 + lane];
      unsigned int w2 = kvb[(unsigned)p2 + lane];
      unsigned int w3 = kvb[(unsigned)p3 + lane];
      edge_update(w0, qdA, sA, aA);
      edge_update(w1, qdA, sA, aA);
      edge_update(w2, qdA, sA, aA);
      edge_update(w3, qdA, sA, aA);
    }
    for (; jA < eA; ++jA) {
      int p = __builtin_amdgcn_readfirstlane(cA[jA]);
      edge_update(kvb[(unsigned)p + lane], qdA, sA, aA);
    }
    int jB = j;
    for (; jB + 4 <= eB; jB += 4) {
      int p0 = __builtin_amdgcn_readfirstlane(cB[jB + 0]);
      int p1 = __builtin_amdgcn_readfirstlane(cB[jB + 1]);
      int p2 = __builtin_amdgcn_readfirstlane(cB[jB + 2]);
      int p3 = __builtin_amdgcn_readfirstlane(cB[jB + 3]);
      unsigned int w0 = kvb[(unsigned)p0 + lane];
      unsigned int w1 = kvb[(unsigned)p1 + lane];
      unsigned int w2 = kvb[(unsigned)p2 + lane];
      unsigned int w3 = kvb[(unsigned)p3 + lane];
      edge_update(w0, qdB, sB, aB);
      edge_update(w1, qdB, sB, aB);
      edge_update(w2, qdB, sB, aB);
      edge_update(w3, qdB, sB, aB);
    }
    for (; jB < eB; ++jB) {
      int p = __builtin_amdgcn_readfirstlane(cB[jB]);
      edge_update(kvb[(unsigned)p + lane], qdB, sB, aB);
    }

    float hvA = (sA > 0.f) ? (aA / sA) : 0.f;
    float hvB = (sB > 0.f) ? (aB / sB) : 0.f;
    float prA = __shfl_xor(hvA, 1, 64);
    float prB = __shfl_xor(hvB, 1, 64);
    if ((lane & 1) == 0) {
      hlds[lrowA * HSTRIDE + (lane >> 1)] =
          f32_to_bf16(hvA) | (f32_to_bf16(prA) << 16);
      hlds[(lrowA + 1) * HSTRIDE + (lane >> 1)] =
          f32_to_bf16(hvB) | (f32_to_bf16(prB) << 16);
    }
  }
  __syncthreads();

  // ---- phase 2: out = (h @ Wa[ty]) * alpha + x * (1-alpha) ----
  const int l15 = lane & 15;
  const int lq = lane >> 4;
  const short8v A0 = *reinterpret_cast<const short8v*>(&hlds[l15 * HSTRIDE + lq * 4]);
  const short8v A1 = *reinterpret_cast<const short8v*>(&hlds[l15 * HSTRIDE + 16 + lq * 4]);

  const int n0 = lst[min(base + lq * 4 + 0, cnt - 1)];
  const int n1 = lst[min(base + lq * 4 + 1, cnt - 1)];
  const int n2 = lst[min(base + lq * 4 + 2, cnt - 1)];
  const int n3 = lst[min(base + lq * 4 + 3, cnt - 1)];

  const float alpha = 1.f / (1.f + __expf(-skip[ty]));
  const float beta = 1.f - alpha;
  const unsigned short* Bb = Wa2b + (size_t)ty * 4096;

  const int colb = wave * 16 + l15;         // wave w owns col-tile w
  const short8v B0 = *reinterpret_cast<const short8v*>(
      Bb + (size_t)colb * 64 + lq * 8);
  const short8v B1 = *reinterpret_cast<const short8v*>(
      Bb + (size_t)colb * 64 + 32 + lq * 8);
  float4v C = {0.f, 0.f, 0.f, 0.f};
  C = __builtin_amdgcn_mfma_f32_16x16x32_bf16(A0, B0, C, 0, 0, 0);
  C = __builtin_amdgcn_mfma_f32_16x16x32_bf16(A1, B1, C, 0, 0, 0);

  const size_t o0 = (size_t)n0 * 64 + colb;
  const size_t o1 = (size_t)n1 * 64 + colb;
  const size_t o2 = (size_t)n2 * 64 + colb;
  const size_t o3 = (size_t)n3 * 64 + colb;
  out[o0] = C[0] * alpha + x[o0] * beta;
  out[o1] = C[1] * alpha + x[o1] * beta;
  out[o2] = C[2] * alpha + x[o2] * beta;
  out[o3] = C[3] * alpha + x[o3] * beta;
}

// ---------------------------------------------------------------------------
extern "C" void kernel_launch(void* const* d_in, const int* in_sizes, int n_in,
                              void* d_out, int out_size, void* d_ws, size_t ws_size,
                              hipStream_t stream) {
  const float* x    = (const float*)d_in[0];
  const float* Wk   = (const float*)d_in[1];
  const float* Wq   = (const float*)d_in[2];
  const float* Wv   = (const float*)d_in[3];
  const float* Wa   = (const float*)d_in[4];
  const float* Ratt = (const float*)d_in[5];
  const float* Rmsg = (const float*)d_in[6];
  const float* pri  = (const float*)d_in[7];
  const float* skip = (const float*)d_in[8];
  const int* ntype  = (const int*)d_in[9];
  const int* etype  = (const int*)d_in[10];
  const int* src    = (const int*)d_in[11];
  const int* dst    = (const int*)d_in[12];
  float* out = (float*)d_out;

  // workspace layout
  unsigned short* qb = (unsigned short*)d_ws;           // N*64 bf16
  unsigned int* kvb = (unsigned int*)(qb + (size_t)N_NODES * 64);  // ET*N*64
  int* deg   = (int*)(kvb + (size_t)ET_TYPES * N_NODES * 64);  // N } zero_kernel
  int* tcnt  = deg + N_NODES;                           // 2  } covers both
  int* tlist = tcnt + 2;                                // 2*N
  int* csr   = tlist + 2 * N_NODES;                     // N*MAXDEG
  unsigned short* M2b = (unsigned short*)
      (((uintptr_t)(csr + (size_t)N_NODES * MAXDEG) + 255) & ~(uintptr_t)255);
  unsigned short* Wa2b = (unsigned short*)
      (((uintptr_t)(M2b + NT_TYPES * M_PER_T) + 255) & ~(uintptr_t)255);

  zero_kernel<<<NB_SCAN, 256, 0, stream>>>(deg);

  prep_kernel<<<NB_SCAN, 256, 0, stream>>>(
      Wk, Wq, Wv, Wa, Ratt, Rmsg, pri, ntype, M2b, Wa2b, tcnt, tlist);

  projscatter_kernel<<<2 * PROJ_GRID + SCAT_GRID, 256, 0, stream>>>(
      x, M2b, tcnt, tlist, qb, kvb, src, dst, etype, deg, csr);

  dim3 agrid(AGG_GRID, NT_TYPES);
  agg_out_kernel<<<agrid, 256, 0, stream>>>(
      qb, (const unsigned int*)kvb, deg, csr, Wa2b, x, skip, tcnt, tlist, out);
}

// Round 20
// 101.975 us; speedup vs baseline: 1.2136x; 1.1361x over previous
//
#include <hip/hip_runtime.h>
#include <math.h>
#include <stdint.h>

#define N_NODES 50000
#define N_EDGES 800000
#define NT_TYPES 2
#define ET_TYPES 2
#define NB_SCAN ((N_NODES + 255) / 256)   // 196
#define M_COLS 320                         // 64 q + 2et*128 interleaved (katt,vmsg)
#define M_PER_T (64 * M_COLS)              // 20480 elems per type
#define PROJ_GRID ((N_NODES + 63) / 64)    // 782 (both types per block now)
#define SCAT_GRID ((N_EDGES + 255) / 256)  // 3125 (R19 lesson: 1 edge/thread = max TLP)
#define AGG_GRID (N_NODES / 16)            // 3125 exactly
#define MAXDEG 64                          // deg ~ Poisson(16): P(>64) ~ 1e-18
#define LOG2E 1.44269504088896f
#define HSTRIDE 36                         // LDS dwords per h row (144B, 16B-aligned)

typedef __attribute__((ext_vector_type(8))) short short8v;   // 8 bf16 (4 VGPR)
typedef __attribute__((ext_vector_type(4))) float float4v;   // MFMA C/D

__device__ __forceinline__ unsigned int f32_to_bf16(float f) {
  unsigned int u = __float_as_uint(f);
  return (u + 0x7FFFu + ((u >> 16) & 1u)) >> 16;   // RNE
}

// Sum over each 16-lane head group via DPP row rotations (ror 8/4/2/1).
__device__ __forceinline__ float row16_sum(float p) {
  int r;
  r = __builtin_amdgcn_update_dpp(0, __float_as_int(p), 0x128, 0xf, 0xf, false);
  p += __int_as_float(r);   // ror:8
  r = __builtin_amdgcn_update_dpp(0, __float_as_int(p), 0x124, 0xf, 0xf, false);
  p += __int_as_float(r);   // ror:4
  r = __builtin_amdgcn_update_dpp(0, __float_as_int(p), 0x122, 0xf, 0xf, false);
  p += __int_as_float(r);   // ror:2
  r = __builtin_amdgcn_update_dpp(0, __float_as_int(p), 0x121, 0xf, 0xf, false);
  p += __int_as_float(r);   // ror:1
  return p;
}

// ---------------------------------------------------------------------------
// L1 (fused, no atomics): zero deg + fold weights (col-major bf16 M2b/Wa2b;
// pri*0.25*log2e folded into katt columns). tlist/tcnt DELETED (R19): proj
// and agg compute both types' MFMA tiles and select per node.
// ---------------------------------------------------------------------------
__global__ void prep_kernel(
    const float* __restrict__ Wk, const float* __restrict__ Wq,
    const float* __restrict__ Wv, const float* __restrict__ Wa,
    const float* __restrict__ Ratt, const float* __restrict__ Rmsg,
    const float* __restrict__ pri,
    unsigned short* __restrict__ M2b, unsigned short* __restrict__ Wa2b,
    int* __restrict__ deg) {
  const int idx = blockIdx.x * 256 + threadIdx.x;
  if (idx < N_NODES) deg[idx] = 0;
  if (idx < NT_TYPES * 4096) {              // Wa -> bf16 column-major
    int t = idx >> 12;
    int rem = idx & 4095;
    int col = rem >> 6, k = rem & 63;
    Wa2b[idx] = (unsigned short)f32_to_bf16(Wa[(size_t)t * 4096 + k * 64 + col]);
  }
  if (idx < NT_TYPES * M_PER_T) {           // folded proj weights, col-major
    int t = idx / M_PER_T;
    int rem = idx % M_PER_T;
    int col = rem / 64;
    int k = rem % 64;
    float val;
    if (col < 64) {
      val = Wq[(size_t)t * 4096 + k * 64 + col];
    } else {
      int cc = col - 64;
      int et = cc >> 7;
      int r = cc & 127;
      int c = r >> 1;
      int half = r & 1;
      int h = c >> 4, f = c & 15;
      const float* W = half ? Wv : Wk;
      const float* R = half ? Rmsg : Ratt;
      float s = 0.f;
#pragma unroll
      for (int d = 0; d < 16; ++d)
        s = fmaf(W[(size_t)t * 4096 + k * 64 + h * 16 + d],
                 R[(((size_t)h * ET_TYPES + et) * 16 + d) * 16 + f], s);
      if (half == 0) s *= pri[h * ET_TYPES + et] * 0.25f * LOG2E;  // fold pri
      val = s;
    }
    M2b[idx] = (unsigned short)f32_to_bf16(val);
  }
}

// ---------------------------------------------------------------------------
// L2 heterogeneous: MFMA proj (natural node order, both-types+select) co-
// scheduled with the edge scatter (1 edge/thread, latency-bound, VALU-idle --
// complementary to proj's MFMA density).
//   blocks [0, PROJ_GRID): per wave 16 consecutive nodes; per col-tile
//     compute C for BOTH type slabs, select per node row.
//   blocks [PROJ_GRID, +SCAT_GRID): csr[dst*64+rank] = (et*N+src)<<6.
// ---------------------------------------------------------------------------
__global__ __launch_bounds__(256) void projscatter_kernel(
    const float* __restrict__ x,
    const unsigned short* __restrict__ M2b,
    const int* __restrict__ ntype,
    unsigned short* __restrict__ qb, unsigned int* __restrict__ kvb,
    const int* __restrict__ src, const int* __restrict__ dst,
    const int* __restrict__ etype, int* __restrict__ deg,
    int* __restrict__ csr) {
  const int bid = blockIdx.x;
  if (bid >= PROJ_GRID) {                   // ---- edge scatter, 1/thread ----
    const int e = (bid - PROJ_GRID) * 256 + threadIdx.x;
    if (e < N_EDGES) {
      int d = dst[e];
      int r = atomicAdd(&deg[d], 1);
      __builtin_nontemporal_store((etype[e] * N_NODES + src[e]) << 6,
                                  &csr[(d << 6) + r]);
    }
    return;
  }
  // ---- MFMA projection, both types ----
  const int wave = threadIdx.x >> 6;
  const int lane = threadIdx.x & 63;
  const int base = bid * 64 + wave * 16;
  const int l15 = lane & 15;
  const int lq = lane >> 4;

  // A fragments: node row read as f32, converted in-register (RNE).
  const int nidA = min(base + l15, N_NODES - 1);
  const float4* xr = reinterpret_cast<const float4*>(x + (size_t)nidA * 64);
  const float4 xa0 = xr[lq * 2 + 0];
  const float4 xa1 = xr[lq * 2 + 1];
  const float4 xb0 = xr[8 + lq * 2 + 0];
  const float4 xb1 = xr[8 + lq * 2 + 1];
  union { short8v v; unsigned int u[4]; } A0u, A1u;
  A0u.u[0] = f32_to_bf16(xa0.x) | (f32_to_bf16(xa0.y) << 16);
  A0u.u[1] = f32_to_bf16(xa0.z) | (f32_to_bf16(xa0.w) << 16);
  A0u.u[2] = f32_to_bf16(xa1.x) | (f32_to_bf16(xa1.y) << 16);
  A0u.u[3] = f32_to_bf16(xa1.z) | (f32_to_bf16(xa1.w) << 16);
  A1u.u[0] = f32_to_bf16(xb0.x) | (f32_to_bf16(xb0.y) << 16);
  A1u.u[1] = f32_to_bf16(xb0.z) | (f32_to_bf16(xb0.w) << 16);
  A1u.u[2] = f32_to_bf16(xb1.x) | (f32_to_bf16(xb1.y) << 16);
  A1u.u[3] = f32_to_bf16(xb1.z) | (f32_to_bf16(xb1.w) << 16);
  const short8v A0 = A0u.v;
  const short8v A1 = A1u.v;

  const int n0 = min(base + lq * 4 + 0, N_NODES - 1);
  const int n1 = min(base + lq * 4 + 1, N_NODES - 1);
  const int n2 = min(base + lq * 4 + 2, N_NODES - 1);
  const int n3 = min(base + lq * 4 + 3, N_NODES - 1);
  const int t0 = ntype[n0], t1 = ntype[n1], t2 = ntype[n2], t3 = ntype[n3];

#pragma unroll
  for (int ct = 0; ct < 20; ++ct) {
    const int colb = ct * 16 + l15;
    const size_t boff = (size_t)colb * 64 + lq * 8;
    const short8v B00 = *reinterpret_cast<const short8v*>(M2b + boff);
    const short8v B01 = *reinterpret_cast<const short8v*>(M2b + boff + 32);
    const short8v B10 = *reinterpret_cast<const short8v*>(M2b + M_PER_T + boff);
    const short8v B11 = *reinterpret_cast<const short8v*>(M2b + M_PER_T + boff + 32);
    float4v C0 = {0.f, 0.f, 0.f, 0.f};
    C0 = __builtin_amdgcn_mfma_f32_16x16x32_bf16(A0, B00, C0, 0, 0, 0);
    C0 = __builtin_amdgcn_mfma_f32_16x16x32_bf16(A1, B01, C0, 0, 0, 0);
    float4v C1 = {0.f, 0.f, 0.f, 0.f};
    C1 = __builtin_amdgcn_mfma_f32_16x16x32_bf16(A0, B10, C1, 0, 0, 0);
    C1 = __builtin_amdgcn_mfma_f32_16x16x32_bf16(A1, B11, C1, 0, 0, 0);

    const float v0 = t0 ? C1[0] : C0[0];
    const float v1 = t1 ? C1[1] : C0[1];
    const float v2 = t2 ? C1[2] : C0[2];
    const float v3 = t3 ? C1[3] : C0[3];

    if (ct < 4) {                           // q columns: bf16 store
      qb[(size_t)n0 * 64 + colb] = (unsigned short)f32_to_bf16(v0);
      qb[(size_t)n1 * 64 + colb] = (unsigned short)f32_to_bf16(v1);
      qb[(size_t)n2 * 64 + colb] = (unsigned short)f32_to_bf16(v2);
      qb[(size_t)n3 * 64 + colb] = (unsigned short)f32_to_bf16(v3);
    } else {                                // kv columns: pack bf16x2 pairs
      const float p0 = __shfl_xor(v0, 1, 64);
      const float p1 = __shfl_xor(v1, 1, 64);
      const float p2 = __shfl_xor(v2, 1, 64);
      const float p3 = __shfl_xor(v3, 1, 64);
      if ((lane & 1) == 0) {                // even lane = katt, partner = vmsg
        const int cc = colb - 64;
        const int et = cc >> 7;
        const int c = (cc & 127) >> 1;
        const size_t b0 = ((size_t)et * N_NODES) * 64 + c;
        kvb[b0 + (size_t)n0 * 64] = f32_to_bf16(v0) | (f32_to_bf16(p0) << 16);
        kvb[b0 + (size_t)n1 * 64] = f32_to_bf16(v1) | (f32_to_bf16(p1) << 16);
        kvb[b0 + (size_t)n2 * 64] = f32_to_bf16(v2) | (f32_to_bf16(p2) << 16);
        kvb[b0 + (size_t)n3 * 64] = f32_to_bf16(v3) | (f32_to_bf16(p3) << 16);
      }
    }
  }
}

// ---------------------------------------------------------------------------
// Fused aggregate + output, natural node order (3125 blocks x 16 nodes, N
// divides exactly). Phase 1: two interleaved node-pairs per wave (8 gathers
// in flight). Phase 2: wave w computes col-tile w for BOTH Wa types (4 MFMAs)
// and selects per node; sigmoid-skip blend with per-node alpha.
// ---------------------------------------------------------------------------
__device__ __forceinline__ void edge_update(unsigned int wrd, float qd,
                                            float& srun, float& acc) {
  float kw = __uint_as_float(wrd << 16);            // low bf16 = katt (scaled)
  float mv = __uint_as_float(wrd & 0xFFFF0000u);    // high bf16 = vmsg
  float w = __builtin_amdgcn_exp2f(row16_sum(kw * qd));
  srun += w;
  acc = fmaf(mv, w, acc);
}

__global__ __launch_bounds__(256) void agg_out_kernel(
    const unsigned short* __restrict__ qb, const unsigned int* __restrict__ kvb,
    const int* __restrict__ deg, const int* __restrict__ csr,
    const unsigned short* __restrict__ Wa2b, const float* __restrict__ x,
    const float* __restrict__ skip, const int* __restrict__ ntype,
    float* __restrict__ out) {
  __shared__ unsigned int hlds[16 * HSTRIDE];
  const int wave = threadIdx.x >> 6;
  const int lane = threadIdx.x & 63;
  const int base = blockIdx.x * 16;

  // ---- phase 1: two interleaved node-pairs per wave ----
  for (int half = 0; half < 2; ++half) {
    const int lrowA = wave * 4 + half * 2;
    const int nA = __builtin_amdgcn_readfirstlane(base + lrowA);
    const int nB = __builtin_amdgcn_readfirstlane(base + lrowA + 1);
    const float qdA = __uint_as_float((unsigned int)qb[(size_t)nA * 64 + lane] << 16);
    const float qdB = __uint_as_float((unsigned int)qb[(size_t)nB * 64 + lane] << 16);
    const int eA = __builtin_amdgcn_readfirstlane(deg[nA]);
    const int eB = __builtin_amdgcn_readfirstlane(deg[nB]);
    const int* cA = csr + (nA << 6);
    const int* cB = csr + (nB << 6);

    float sA = 0.f, aA = 0.f, sB = 0.f, aB = 0.f;
    const int m = min(eA, eB);
    int j = 0;
    for (; j + 4 <= m; j += 4) {            // joint: 8 gathers in flight
      int pA0 = __builtin_amdgcn_readfirstlane(cA[j + 0]);
      int pA1 = __builtin_amdgcn_readfirstlane(cA[j + 1]);
      int pA2 = __builtin_amdgcn_readfirstlane(cA[j + 2]);
      int pA3 = __builtin_amdgcn_readfirstlane(cA[j + 3]);
      int pB0 = __builtin_amdgcn_readfirstlane(cB[j + 0]);
      int pB1 = __builtin_amdgcn_readfirstlane(cB[j + 1]);
      int pB2 = __builtin_amdgcn_readfirstlane(cB[j + 2]);
      int pB3 = __builtin_amdgcn_readfirstlane(cB[j + 3]);
      unsigned int wA0 = kvb[(unsigned)pA0 + lane];
      unsigned int wA1 = kvb[(unsigned)pA1 + lane];
      unsigned int wA2 = kvb[(unsigned)pA2 + lane];
      unsigned int wA3 = kvb[(unsigned)pA3 + lane];
      unsigned int wB0 = kvb[(unsigned)pB0 + lane];
      unsigned int wB1 = kvb[(unsigned)pB1 + lane];
      unsigned int wB2 = kvb[(unsigned)pB2 + lane];
      unsigned int wB3 = kvb[(unsigned)pB3 + lane];
      edge_update(wA0, qdA, sA, aA);
      edge_update(wB0, qdB, sB, aB);
      edge_update(wA1, qdA, sA, aA);
      edge_update(wB1, qdB, sB, aB);
      edge_update(wA2, qdA, sA, aA);
      edge_update(wB2, qdB, sB, aB);
      edge_update(wA3, qdA, sA, aA);
      edge_update(wB3, qdB, sB, aB);
    }
    int jA = j;
    for (; jA + 4 <= eA; jA += 4) {
      int p0 = __builtin_amdgcn_readfirstlane(cA[jA + 0]);
      int p1 = __builtin_amdgcn_readfirstlane(cA[jA + 1]);
      int p2 = __builtin_amdgcn_readfirstlane(cA[jA + 2]);
      int p3 = __builtin_amdgcn_readfirstlane(cA[jA + 3]);
      unsigned int w0 = kvb[(unsigned)p0 + lane];
      unsigned int w1 = kvb[(unsigned)p1 + lane];
      unsigned int w2 = kvb[(unsigned)p2 + lane];
      unsigned int w3 = kvb[(unsigned)p3 + lane];
      edge_update(w0, qdA, sA, aA);
      edge_update(w1, qdA, sA, aA);
      edge_update(w2, qdA, sA, aA);
      edge_update(w3, qdA, sA, aA);
    }
    for (; jA < eA; ++jA) {
      int p = __builtin_amdgcn_readfirstlane(cA[jA]);
      edge_update(kvb[(unsigned)p + lane], qdA, sA, aA);
    }
    int jB = j;
    for (; jB + 4 <= eB; jB += 4) {
      int p0 = __builtin_amdgcn_readfirstlane(cB[jB + 0]);
      int p1 = __builtin_amdgcn_readfirstlane(cB[jB + 1]);
      int p2 = __builtin_amdgcn_readfirstlane(cB[jB + 2]);
      int p3 = __builtin_amdgcn_readfirstlane(cB[jB + 3]);
      unsigned int w0 = kvb[(unsigned)p0 + lane];
      unsigned int w1 = kvb[(unsigned)p1 + lane];
      unsigned int w2 = kvb[(unsigned)p2 + lane];
      unsigned int w3 = kvb[(unsigned)p3 + lane];
      edge_update(w0, qdB, sB, aB);
      edge_update(w1, qdB, sB, aB);
      edge_update(w2, qdB, sB, aB);
      edge_update(w3, qdB, sB, aB);
    }
    for (; jB < eB; ++jB) {
      int p = __builtin_amdgcn_readfirstlane(cB[jB]);
      edge_update(kvb[(unsigned)p + lane], qdB, sB, aB);
    }

    float hvA = (sA > 0.f) ? (aA / sA) : 0.f;
    float hvB = (sB > 0.f) ? (aB / sB) : 0.f;
    float prA = __shfl_xor(hvA, 1, 64);
    float prB = __shfl_xor(hvB, 1, 64);
    if ((lane & 1) == 0) {
      hlds[lrowA * HSTRIDE + (lane >> 1)] =
          f32_to_bf16(hvA) | (f32_to_bf16(prA) << 16);
      hlds[(lrowA + 1) * HSTRIDE + (lane >> 1)] =
          f32_to_bf16(hvB) | (f32_to_bf16(prB) << 16);
    }
  }
  __syncthreads();

  // ---- phase 2: out = (h @ Wa[ntype]) * alpha + x * (1-alpha), both types ----
  const int l15 = lane & 15;
  const int lq = lane >> 4;
  const short8v A0 = *reinterpret_cast<const short8v*>(&hlds[l15 * HSTRIDE + lq * 4]);
  const short8v A1 = *reinterpret_cast<const short8v*>(&hlds[l15 * HSTRIDE + 16 + lq * 4]);

  const int n0 = base + lq * 4 + 0;
  const int n1 = base + lq * 4 + 1;
  const int n2 = base + lq * 4 + 2;
  const int n3 = base + lq * 4 + 3;
  const int t0 = ntype[n0], t1 = ntype[n1], t2 = ntype[n2], t3 = ntype[n3];

  const float alpha0 = 1.f / (1.f + __expf(-skip[0]));
  const float alpha1 = 1.f / (1.f + __expf(-skip[1]));

  const int colb = wave * 16 + l15;         // wave w owns col-tile w
  const size_t boff = (size_t)colb * 64 + lq * 8;
  const short8v B00 = *reinterpret_cast<const short8v*>(Wa2b + boff);
  const short8v B01 = *reinterpret_cast<const short8v*>(Wa2b + boff + 32);
  const short8v B10 = *reinterpret_cast<const short8v*>(Wa2b + 4096 + boff);
  const short8v B11 = *reinterpret_cast<const short8v*>(Wa2b + 4096 + boff + 32);
  float4v C0 = {0.f, 0.f, 0.f, 0.f};
  C0 = __builtin_amdgcn_mfma_f32_16x16x32_bf16(A0, B00, C0, 0, 0, 0);
  C0 = __builtin_amdgcn_mfma_f32_16x16x32_bf16(A1, B01, C0, 0, 0, 0);
  float4v C1 = {0.f, 0.f, 0.f, 0.f};
  C1 = __builtin_amdgcn_mfma_f32_16x16x32_bf16(A0, B10, C1, 0, 0, 0);
  C1 = __builtin_amdgcn_mfma_f32_16x16x32_bf16(A1, B11, C1, 0, 0, 0);

  const float al0 = t0 ? alpha1 : alpha0;
  const float al1 = t1 ? alpha1 : alpha0;
  const float al2 = t2 ? alpha1 : alpha0;
  const float al3 = t3 ? alpha1 : alpha0;
  const float v0 = t0 ? C1[0] : C0[0];
  const float v1 = t1 ? C1[1] : C0[1];
  const float v2 = t2 ? C1[2] : C0[2];
  const float v3 = t3 ? C1[3] : C0[3];

  const size_t o0 = (size_t)n0 * 64 + colb;
  const size_t o1 = (size_t)n1 * 64 + colb;
  const size_t o2 = (size_t)n2 * 64 + colb;
  const size_t o3 = (size_t)n3 * 64 + colb;
  out[o0] = v0 * al0 + x[o0] * (1.f - al0);
  out[o1] = v1 * al1 + x[o1] * (1.f - al1);
  out[o2] = v2 * al2 + x[o2] * (1.f - al2);
  out[o3] = v3 * al3 + x[o3] * (1.f - al3);
}

// ---------------------------------------------------------------------------
extern "C" void kernel_launch(void* const* d_in, const int* in_sizes, int n_in,
                              void* d_out, int out_size, void* d_ws, size_t ws_size,
                              hipStream_t stream) {
  const float* x    = (const float*)d_in[0];
  const float* Wk   = (const float*)d_in[1];
  const float* Wq   = (const float*)d_in[2];
  const float* Wv   = (const float*)d_in[3];
  const float* Wa   = (const float*)d_in[4];
  const float* Ratt = (const float*)d_in[5];
  const float* Rmsg = (const float*)d_in[6];
  const float* pri  = (const float*)d_in[7];
  const float* skip = (const float*)d_in[8];
  const int* ntype  = (const int*)d_in[9];
  const int* etype  = (const int*)d_in[10];
  const int* src    = (const int*)d_in[11];
  const int* dst    = (const int*)d_in[12];
  float* out = (float*)d_out;

  // workspace layout
  unsigned short* qb = (unsigned short*)d_ws;           // N*64 bf16
  unsigned int* kvb = (unsigned int*)(qb + (size_t)N_NODES * 64);  // ET*N*64
  int* deg = (int*)(kvb + (size_t)ET_TYPES * N_NODES * 64);  // N (zeroed in prep)
  int* csr = deg + N_NODES;                             // N*MAXDEG
  unsigned short* M2b = (unsigned short*)
      (((uintptr_t)(csr + (size_t)N_NODES * MAXDEG) + 255) & ~(uintptr_t)255);
  unsigned short* Wa2b = (unsigned short*)
      (((uintptr_t)(M2b + NT_TYPES * M_PER_T) + 255) & ~(uintptr_t)255);

  prep_kernel<<<NB_SCAN, 256, 0, stream>>>(
      Wk, Wq, Wv, Wa, Ratt, Rmsg, pri, M2b, Wa2b, deg);

  projscatter_kernel<<<PROJ_GRID + SCAT_GRID, 256, 0, stream>>>(
      x, M2b, ntype, qb, kvb, src, dst, etype, deg, csr);

  agg_out_kernel<<<AGG_GRID, 256, 0, stream>>>(
      qb, (const unsigned int*)kvb, deg, csr, Wa2b, x, skip, ntype, out);
}